// Round 17
// baseline (423.360 us; speedup 1.0000x reference)
//
#include <hip/hip_runtime.h>
#include <hip/hip_bf16.h>
#include <math.h>

#define NTOK 49
#define NH 12
#define HD 32
#define CDIM 384
#define NWIN 64
#define BWIN 2048
#define QKVROW 1152
#define BCROW 52      // bias row stride (floats), 16B-aligned
#define BCTILE 2560   // bias tile stride (floats), 16B-aligned

typedef __bf16 bf16x8 __attribute__((ext_vector_type(8)));
typedef __bf16 bf16x4 __attribute__((ext_vector_type(4)));
typedef float f32x4 __attribute__((ext_vector_type(4)));

__device__ __forceinline__ void gload_lds16(const void* g, void* l) {
    __builtin_amdgcn_global_load_lds((const __attribute__((address_space(1))) void*)g,
                                     (__attribute__((address_space(3))) void*)l, 16, 0, 0);
}

__device__ __forceinline__ void cvt8(const float* src, __bf16* dst, int i) {
    f32x4 a = *(const f32x4*)(src + (size_t)i * 8);
    f32x4 b = *(const f32x4*)(src + (size_t)i * 8 + 4);
    bf16x8 o;
#pragma unroll
    for (int e = 0; e < 4; ++e) { o[e] = (__bf16)a[e]; o[e + 4] = (__bf16)b[e]; }
    *(bf16x8*)(dst + (size_t)i * 8) = o;
}

// ---------------- prep1: block-partitioned {cvt x, cvt qkv_w, cvt proj_w, cpb MLP} ----------------
#define XBLKS 18816   // 100352*384/8/256
__global__ void prep1(const float* __restrict__ x, __bf16* __restrict__ xbf,
                      const float* __restrict__ qkv_w, __bf16* __restrict__ qkv_wb,
                      const float* __restrict__ proj_w, __bf16* __restrict__ proj_wb,
                      const float* __restrict__ w1, const float* __restrict__ b1,
                      const float* __restrict__ w2, float* __restrict__ bias_tab) {
    const int blk = blockIdx.x, tid = threadIdx.x;
    if (blk < XBLKS) {
        cvt8(x, xbf, blk * 256 + tid);
    } else if (blk < XBLKS + 216) {
        cvt8(qkv_w, qkv_wb, (blk - XBLKS) * 256 + tid);
    } else if (blk < XBLKS + 288) {
        cvt8(proj_w, proj_wb, (blk - XBLKS - 216) * 256 + tid);
    } else {
        int t = (blk - XBLKS - 288) * 256 + tid;
        if (t >= 169 * NH) return;
        int r = t / NH, h = t - (t / NH) * NH;
        int i = r / 13, j = r - (r / 13) * 13;
        float a0 = (float)(i - 6) * (8.0f / 6.0f);
        float a1 = (float)(j - 6) * (8.0f / 6.0f);
        float c0 = copysignf(log2f(fabsf(a0) + 1.0f) * (1.0f / 3.0f), a0);
        float c1 = copysignf(log2f(fabsf(a1) + 1.0f) * (1.0f / 3.0f), a1);
        float sum = 0.f;
        for (int k = 0; k < 512; ++k) {
            float hid = c0 * w1[2 * k] + c1 * w1[2 * k + 1] + b1[k];
            hid = fmaxf(hid, 0.f);
            sum += hid * w2[h * 512 + k];
        }
        bias_tab[r * NH + h] = sum;
    }
}

// ---- prep2: biasC tile [w][h], layout [q][BCROW] (k fastest): 16*sigmoid(cpb)+mask ----
__global__ void prep2(const float* __restrict__ bias_tab, const float* __restrict__ mask,
                      float* __restrict__ biasC) {
    int idx = blockIdx.x * blockDim.x + threadIdx.x;
    if (idx >= NWIN * NH * NTOK * BCROW) return;
    const int per_t = NTOK * BCROW;
    int wh = idx / per_t;
    int rem = idx - wh * per_t;
    int q = rem / BCROW, k = rem - (rem / BCROW) * BCROW;
    int w = wh / NH, h = wh - (wh / NH) * NH;
    float* dst = biasC + (size_t)wh * BCTILE + q * BCROW + k;
    if (k < NTOK) {
        int chi = q / 7, cwi = q - (q / 7) * 7;
        int chj = k / 7, cwj = k - (k / 7) * 7;
        int rpi = (chi - chj + 6) * 13 + (cwi - cwj + 6);
        float r = bias_tab[rpi * NH + h];
        *dst = 16.f / (1.f + __expf(-r)) + mask[(w * NTOK + q) * NTOK + k];
    } else {
        *dst = 0.f;
    }
}

// ---------------- MFMA GEMM (R11 verbatim): 3-buffer counted-vmcnt, all-bf16 ----------------
template <int MODE, int NBY>
__global__ __launch_bounds__(256) void gemm6(
    const __bf16* __restrict__ A, const __bf16* __restrict__ Bw,
    const float* __restrict__ qbias, const float* __restrict__ vbias,
    __bf16* __restrict__ qkvout,
    float* __restrict__ fout, const float* __restrict__ fbias)
{
    __shared__ __bf16 As[3][128 * 32];
    __shared__ __bf16 Bs[3][128 * 32];
    const int tid = threadIdx.x;
    const int chunk = (784 * NBY) >> 3;
    const int wg = (blockIdx.x & 7) * chunk + (blockIdx.x >> 3);
    const int gx = wg / NBY, gy = wg - (wg / NBY) * NBY;
    const int lane = tid & 63;
    const int wid = tid >> 6;
    const int wr = (wid >> 1) * 64;
    const int wc = (wid & 1) * 64;
    const int fr = lane & 15;
    const int fq = lane >> 4;

    f32x4 acc[4][4];
#pragma unroll
    for (int m = 0; m < 4; ++m)
#pragma unroll
        for (int n = 0; n < 4; ++n)
            acc[m][n] = (f32x4){0.f, 0.f, 0.f, 0.f};

    const int srow0 = tid >> 2, scp0 = tid & 3;
    const int srow1 = (256 + tid) >> 2;
    const size_t ar0 = (size_t)(gx * 128 + srow0) * CDIM + (scp0 ^ ((srow0 >> 1) & 3)) * 8;
    const size_t ar1 = (size_t)(gx * 128 + srow1) * CDIM + (scp0 ^ ((srow1 >> 1) & 3)) * 8;
    const size_t br0 = (size_t)(gy * 128 + srow0) * CDIM + (scp0 ^ ((srow0 >> 1) & 3)) * 8;
    const size_t br1 = (size_t)(gy * 128 + srow1) * CDIM + (scp0 ^ ((srow1 >> 1) & 3)) * 8;
    const int ls0 = tid * 16, ls1 = (256 + tid) * 16;

#define STAGE(ti, buf) do {                                              \
        const int kk_ = (ti) * 32;                                       \
        gload_lds16(A + ar0 + kk_, (char*)&As[buf][0] + ls0);            \
        gload_lds16(A + ar1 + kk_, (char*)&As[buf][0] + ls1);            \
        gload_lds16(Bw + br0 + kk_, (char*)&Bs[buf][0] + ls0);           \
        gload_lds16(Bw + br1 + kk_, (char*)&Bs[buf][0] + ls1);           \
    } while (0)

    STAGE(0, 0);
    STAGE(1, 1);

#pragma unroll
    for (int t = 0; t < 12; ++t) {
        if (t < 11) asm volatile("s_waitcnt vmcnt(4)" ::: "memory");
        else        asm volatile("s_waitcnt vmcnt(0)" ::: "memory");
        __builtin_amdgcn_s_barrier();
        if (t + 2 < 12) STAGE(t + 2, (t + 2) % 3);
        const int cur = t % 3;
        bf16x8 af[4], bfr[4];
#pragma unroll
        for (int m = 0; m < 4; ++m) {
            const int row = wr + m * 16 + fr;
            af[m] = *(const bf16x8*)&As[cur][row * 32 + (fq ^ ((row >> 1) & 3)) * 8];
        }
#pragma unroll
        for (int n = 0; n < 4; ++n) {
            const int row = wc + n * 16 + fr;
            bfr[n] = *(const bf16x8*)&Bs[cur][row * 32 + (fq ^ ((row >> 1) & 3)) * 8];
        }
#pragma unroll
        for (int m = 0; m < 4; ++m)
#pragma unroll
            for (int n = 0; n < 4; ++n)
                acc[m][n] = __builtin_amdgcn_mfma_f32_16x16x32_bf16(af[m], bfr[n], acc[m][n], 0, 0, 0);
    }
#undef STAGE

    if (MODE == 0) {
        const int colbase = gy * 128;
        const int part = colbase / CDIM;
        const int pcolbase = colbase - part * CDIM;
#pragma unroll
        for (int m = 0; m < 4; ++m) {
#pragma unroll
            for (int r = 0; r < 4; ++r) {
                const int row = gx * 128 + wr + m * 16 + fq * 4 + r;
                __bf16* orow = qkvout + (size_t)row * QKVROW + colbase + wc;
#pragma unroll
                for (int n = 0; n < 4; ++n) {
                    const int pcol = pcolbase + wc + n * 16 + fr;
                    float val = acc[m][n][r];
                    if (part == 0) val += qbias[pcol];
                    if (part == 2) val += vbias[pcol];
                    orow[n * 16 + fr] = (__bf16)val;
                }
            }
        }
    } else {
#pragma unroll
        for (int m = 0; m < 4; ++m) {
#pragma unroll
            for (int r = 0; r < 4; ++r) {
                const int row = gx * 128 + wr + m * 16 + fq * 4 + r;
                float* orow = fout + (size_t)row * CDIM + gy * 128 + wc;
#pragma unroll
                for (int n = 0; n < 4; ++n) {
                    const int col = gy * 128 + wc + n * 16 + fr;
                    orow[n * 16 + fr] = acc[m][n][r] + fbias[col];
                }
            }
        }
    }
}

// ---------------- attention v6: sequential bounce buffer (K->Q->P share 5 KB) ----------------
// Per-wave LDS 10496 B: bounce @0 (5120: K staging, then Q staging, then P-half),
// V @5120 (5120), invk @10240 (256 B, consumed as f32x4). Same-wave DS ordering makes
// the sequential overwrites safe (all consumers in-wave; compiler can't prove disjoint
// offsets so program order is preserved). Block LDS 42 KB -> 3 blocks/CU (was 2).
// Bias path = R16 f32x4 [q][BCROW] tiles (verified win). invq via shfl (attn5-verified).
#define AWREG 10496
__global__ __launch_bounds__(256) void attn6(
    const __bf16* __restrict__ qkv, const float* __restrict__ biasC,
    const float* __restrict__ lscale, __bf16* __restrict__ aout)
{
    __shared__ char smem[4 * AWREG];
    const int tid = threadIdx.x;
    const int wid = tid >> 6, lane = tid & 63;
    const int bh = blockIdx.x * 4 + wid;
    const int b = bh / NH, h = bh - b * NH;
    const int w = b & (NWIN - 1);
    const int c = lane & 15, g = lane >> 4;

    char* base = smem + wid * AWREG;
    __bf16* Bn = (__bf16*)base;            // bounce: K -> Q -> P
    __bf16* Vl = (__bf16*)(base + 5120);   // [64][40]
    float* invk = (float*)(base + 10240);  // [64]

    const float sc = __expf(fminf(lscale[h], 4.6051702f));

    bf16x8 z;
#pragma unroll
    for (int e = 0; e < 8; ++e) z[e] = (__bf16)0.f;

    const int row = lane;
    const size_t rb = ((size_t)b * NTOK + row) * QKVROW + h * HD;

    // ---- V staging (lane = row, coalesced 64 B/lane) ----
    {
        bf16x8 t[4];
        if (row < NTOK) {
#pragma unroll
            for (int ch = 0; ch < 4; ++ch) t[ch] = *(const bf16x8*)(qkv + rb + 2 * CDIM + ch * 8);
        } else {
#pragma unroll
            for (int ch = 0; ch < 4; ++ch) t[ch] = z;
        }
#pragma unroll
        for (int ch = 0; ch < 4; ++ch) *(bf16x8*)&Vl[row * 40 + ch * 8] = t[ch];
    }

    // ---- K staging into bounce + invk[row] ----
    {
        bf16x8 t[4];
        float ss = 0.f;
        if (row < NTOK) {
#pragma unroll
            for (int ch = 0; ch < 4; ++ch) {
                t[ch] = *(const bf16x8*)(qkv + rb + CDIM + ch * 8);
#pragma unroll
                for (int e = 0; e < 8; ++e) { float f = (float)t[ch][e]; ss += f * f; }
            }
        } else {
#pragma unroll
            for (int ch = 0; ch < 4; ++ch) t[ch] = z;
        }
#pragma unroll
        for (int ch = 0; ch < 4; ++ch) *(bf16x8*)&Bn[row * 40 + ch * 8] = t[ch];
        invk[row] = 1.f / fmaxf(sqrtf(ss), 1e-12f);
    }

    // ---- K fragments from bounce ----
    bf16x8 kfr[4];
#pragma unroll
    for (int mt = 0; mt < 4; ++mt) kfr[mt] = *(const bf16x8*)&Bn[(mt * 16 + c) * 40 + g * 8];

    // ---- Q staging into bounce (overwrites K; kfr already in regs) + ssq ----
    float ssq = 0.f;
    {
        bf16x8 t[4];
        if (row < NTOK) {
#pragma unroll
            for (int ch = 0; ch < 4; ++ch) {
                t[ch] = *(const bf16x8*)(qkv + rb + ch * 8);
#pragma unroll
                for (int e = 0; e < 8; ++e) { float f = (float)t[ch][e]; ssq += f * f; }
            }
        } else {
#pragma unroll
            for (int ch = 0; ch < 4; ++ch) t[ch] = z;
        }
#pragma unroll
        for (int ch = 0; ch < 4; ++ch) *(bf16x8*)&Bn[row * 40 + ch * 8] = t[ch];
    }

    // ---- Q fragments from bounce + invq via shfl ----
    bf16x8 qfr[4];
    float ivq[4];
#pragma unroll
    for (int nt = 0; nt < 4; ++nt) {
        qfr[nt] = *(const bf16x8*)&Bn[(nt * 16 + c) * 40 + g * 8];
        float ss = __shfl(ssq, nt * 16 + c);
        ivq[nt] = sc / fmaxf(sqrtf(ss), 1e-12f);
    }

    // ---- S^T = K·Q^T ----
    f32x4 S[4][4];
#pragma unroll
    for (int mt = 0; mt < 4; ++mt)
#pragma unroll
        for (int nt = 0; nt < 4; ++nt) {
            S[mt][nt] = (f32x4){0.f, 0.f, 0.f, 0.f};
            S[mt][nt] = __builtin_amdgcn_mfma_f32_16x16x32_bf16(kfr[mt], qfr[nt], S[mt][nt], 0, 0, 0);
        }

    // ---- scale + combined bias (f32x4 loads; invk as f32x4 LDS read) ----
    const float* bc = biasC + (size_t)(w * NH + h) * BCTILE;
#pragma unroll
    for (int mt = 0; mt < 4; ++mt) {
        const int k0 = mt * 16 + g * 4;
        const f32x4 ivkv = *(const f32x4*)&invk[k0];
#pragma unroll
        for (int nt = 0; nt < 4; ++nt) {
            const int q = nt * 16 + c;
            f32x4 bv = (f32x4){0.f, 0.f, 0.f, 0.f};
            if (q < NTOK) bv = *(const f32x4*)(bc + q * BCROW + k0);
#pragma unroll
            for (int r = 0; r < 4; ++r) {
                const int k = k0 + r;
                float v = S[mt][nt][r] * ivkv[r] * ivq[nt];
                if (k < NTOK) {
                    if (q < NTOK) v += bv[r];
                } else {
                    v = -1e30f;
                }
                S[mt][nt][r] = v;
            }
        }
    }

    // ---- softmax over k ----
    float rs[4];
#pragma unroll
    for (int nt = 0; nt < 4; ++nt) {
        float m = -1e30f;
#pragma unroll
        for (int mt = 0; mt < 4; ++mt)
#pragma unroll
            for (int r = 0; r < 4; ++r) m = fmaxf(m, S[mt][nt][r]);
        m = fmaxf(m, __shfl_xor(m, 16));
        m = fmaxf(m, __shfl_xor(m, 32));
        float s = 0.f;
#pragma unroll
        for (int mt = 0; mt < 4; ++mt)
#pragma unroll
            for (int r = 0; r < 4; ++r) {
                float e = __expf(S[mt][nt][r] - m);
                S[mt][nt][r] = e;
                s += e;
            }
        s += __shfl_xor(s, 16);
        s += __shfl_xor(s, 32);
        rs[nt] = 1.f / s;
    }

    // ---- O = P·V per 32-k half; P-half in bounce (overwrites Q; qfr consumed) ----
    f32x4 O[4][2];
#pragma unroll
    for (int mt = 0; mt < 4; ++mt)
#pragma unroll
        for (int dt = 0; dt < 2; ++dt) O[mt][dt] = (f32x4){0.f, 0.f, 0.f, 0.f};

#pragma unroll
    for (int kt = 0; kt < 2; ++kt) {
#pragma unroll
        for (int mtl = 0; mtl < 2; ++mtl) {
            const int mt = kt * 2 + mtl;
#pragma unroll
            for (int nt = 0; nt < 4; ++nt) {
                bf16x4 pk;
#pragma unroll
                for (int r = 0; r < 4; ++r) pk[r] = (__bf16)(S[mt][nt][r] * rs[nt]);
                *(bf16x4*)((char*)Bn + (nt * 16 + c) * 80 + (mtl * 16 + g * 4) * 2) = pk;
            }
        }
        bf16x8 vfr[2];
#pragma unroll
        for (int dt = 0; dt < 2; ++dt) {
            bf16x8 t;
#pragma unroll
            for (int e = 0; e < 8; ++e) t[e] = Vl[(kt * 32 + g * 8 + e) * 40 + dt * 16 + c];
            vfr[dt] = t;
        }
#pragma unroll
        for (int mtO = 0; mtO < 4; ++mtO) {
            bf16x8 pfr = *(const bf16x8*)((char*)Bn + (mtO * 16 + c) * 80 + g * 16);
#pragma unroll
            for (int dt = 0; dt < 2; ++dt)
                O[mtO][dt] = __builtin_amdgcn_mfma_f32_16x16x32_bf16(pfr, vfr[dt], O[mtO][dt], 0, 0, 0);
        }
    }

    // ---- store O rows q<49 ----
#pragma unroll
    for (int mt = 0; mt < 4; ++mt)
#pragma unroll
        for (int r = 0; r < 4; ++r) {
            const int q = mt * 16 + g * 4 + r;
            if (q < NTOK) {
                const size_t off = ((size_t)b * NTOK + q) * CDIM + h * HD;
                aout[off + c] = (__bf16)O[mt][0][r];
                aout[off + 16 + c] = (__bf16)O[mt][1][r];
            }
        }
}

extern "C" void kernel_launch(void* const* d_in, const int* in_sizes, int n_in,
                              void* d_out, int out_size, void* d_ws, size_t ws_size,
                              hipStream_t stream) {
    const float* x      = (const float*)d_in[0];
    const float* mask   = (const float*)d_in[1];
    const float* qkv_w  = (const float*)d_in[2];
    const float* q_bias = (const float*)d_in[3];
    const float* v_bias = (const float*)d_in[4];
    const float* lscale = (const float*)d_in[5];
    const float* cpb_w1 = (const float*)d_in[6];
    const float* cpb_b1 = (const float*)d_in[7];
    const float* cpb_w2 = (const float*)d_in[8];
    const float* proj_w = (const float*)d_in[9];
    const float* proj_b = (const float*)d_in[10];
    float* out = (float*)d_out;

    const size_t NROWS = (size_t)BWIN * NTOK;           // 100352
    __bf16* qkvbuf  = (__bf16*)d_ws;                    // flat [100352][1152]
    __bf16* xbf     = qkvbuf + NROWS * QKVROW;          // x bf16; reused as attn out
    __bf16* aoutbuf = xbf;                              // alias: lifetimes disjoint
    __bf16* qkv_wb  = xbf + NROWS * CDIM;
    __bf16* proj_wb = qkv_wb + QKVROW * CDIM;
    float*  bias_tab = (float*)(proj_wb + CDIM * CDIM); // 169*12
    float*  biasC   = bias_tab + 169 * NH;              // 768 tiles x BCTILE f32 (7.9 MB)

    hipLaunchKernelGGL(prep1, dim3(XBLKS + 296), dim3(256), 0, stream,
                       x, xbf, qkv_w, qkv_wb, proj_w, proj_wb,
                       cpb_w1, cpb_b1, cpb_w2, bias_tab);
    hipLaunchKernelGGL(prep2, dim3((NWIN * NH * NTOK * BCROW + 255) / 256), dim3(256), 0, stream,
                       bias_tab, mask, biasC);
    hipLaunchKernelGGL((gemm6<0, 9>), dim3(784 * 9), dim3(256), 0, stream,
                       xbf, qkv_wb, q_bias, v_bias, qkvbuf, (float*)nullptr,
                       (const float*)nullptr);
    hipLaunchKernelGGL(attn6, dim3(BWIN * NH / 4), dim3(256), 0, stream,
                       qkvbuf, biasC, lscale, aoutbuf);
    hipLaunchKernelGGL((gemm6<1, 3>), dim3(784 * 3), dim3(256), 0, stream,
                       aoutbuf, proj_wb, (const float*)nullptr, (const float*)nullptr,
                       (__bf16*)nullptr, out, proj_b);
}

// Round 18
// 422.165 us; speedup vs baseline: 1.0028x; 1.0028x over previous
//
#include <hip/hip_runtime.h>
#include <hip/hip_bf16.h>
#include <math.h>

#define NTOK 49
#define NH 12
#define HD 32
#define CDIM 384
#define NWIN 64
#define BWIN 2048
#define QKVROW 1152
#define BCROW 52      // bias row stride (floats), 16B-aligned
#define BCTILE 2560   // bias tile stride (floats), 16B-aligned

typedef __bf16 bf16x8 __attribute__((ext_vector_type(8)));
typedef __bf16 bf16x4 __attribute__((ext_vector_type(4)));
typedef float f32x4 __attribute__((ext_vector_type(4)));

__device__ __forceinline__ void gload_lds16(const void* g, void* l) {
    __builtin_amdgcn_global_load_lds((const __attribute__((address_space(1))) void*)g,
                                     (__attribute__((address_space(3))) void*)l, 16, 0, 0);
}

__device__ __forceinline__ void cvt8(const float* src, __bf16* dst, int i) {
    f32x4 a = *(const f32x4*)(src + (size_t)i * 8);
    f32x4 b = *(const f32x4*)(src + (size_t)i * 8 + 4);
    bf16x8 o;
#pragma unroll
    for (int e = 0; e < 4; ++e) { o[e] = (__bf16)a[e]; o[e + 4] = (__bf16)b[e]; }
    *(bf16x8*)(dst + (size_t)i * 8) = o;
}

// ---------------- prep1: block-partitioned {cvt x, cvt qkv_w, cvt proj_w, cpb MLP} ----------------
#define XBLKS 18816   // 100352*384/8/256
__global__ void prep1(const float* __restrict__ x, __bf16* __restrict__ xbf,
                      const float* __restrict__ qkv_w, __bf16* __restrict__ qkv_wb,
                      const float* __restrict__ proj_w, __bf16* __restrict__ proj_wb,
                      const float* __restrict__ w1, const float* __restrict__ b1,
                      const float* __restrict__ w2, float* __restrict__ bias_tab) {
    const int blk = blockIdx.x, tid = threadIdx.x;
    if (blk < XBLKS) {
        cvt8(x, xbf, blk * 256 + tid);
    } else if (blk < XBLKS + 216) {
        cvt8(qkv_w, qkv_wb, (blk - XBLKS) * 256 + tid);
    } else if (blk < XBLKS + 288) {
        cvt8(proj_w, proj_wb, (blk - XBLKS - 216) * 256 + tid);
    } else {
        int t = (blk - XBLKS - 288) * 256 + tid;
        if (t >= 169 * NH) return;
        int r = t / NH, h = t - (t / NH) * NH;
        int i = r / 13, j = r - (r / 13) * 13;
        float a0 = (float)(i - 6) * (8.0f / 6.0f);
        float a1 = (float)(j - 6) * (8.0f / 6.0f);
        float c0 = copysignf(log2f(fabsf(a0) + 1.0f) * (1.0f / 3.0f), a0);
        float c1 = copysignf(log2f(fabsf(a1) + 1.0f) * (1.0f / 3.0f), a1);
        float sum = 0.f;
        for (int k = 0; k < 512; ++k) {
            float hid = c0 * w1[2 * k] + c1 * w1[2 * k + 1] + b1[k];
            hid = fmaxf(hid, 0.f);
            sum += hid * w2[h * 512 + k];
        }
        bias_tab[r * NH + h] = sum;
    }
}

// ---- prep2: biasC tile [w][h], layout [q][BCROW] (k fastest): 16*sigmoid(cpb)+mask ----
__global__ void prep2(const float* __restrict__ bias_tab, const float* __restrict__ mask,
                      float* __restrict__ biasC) {
    int idx = blockIdx.x * blockDim.x + threadIdx.x;
    if (idx >= NWIN * NH * NTOK * BCROW) return;
    const int per_t = NTOK * BCROW;
    int wh = idx / per_t;
    int rem = idx - wh * per_t;
    int q = rem / BCROW, k = rem - (rem / BCROW) * BCROW;
    int w = wh / NH, h = wh - (wh / NH) * NH;
    float* dst = biasC + (size_t)wh * BCTILE + q * BCROW + k;
    if (k < NTOK) {
        int chi = q / 7, cwi = q - (q / 7) * 7;
        int chj = k / 7, cwj = k - (k / 7) * 7;
        int rpi = (chi - chj + 6) * 13 + (cwi - cwj + 6);
        float r = bias_tab[rpi * NH + h];
        *dst = 16.f / (1.f + __expf(-r)) + mask[(w * NTOK + q) * NTOK + k];
    } else {
        *dst = 0.f;
    }
}

// ---------------- MFMA GEMM (R11 verbatim): 3-buffer counted-vmcnt, all-bf16 ----------------
template <int MODE, int NBY>
__global__ __launch_bounds__(256) void gemm6(
    const __bf16* __restrict__ A, const __bf16* __restrict__ Bw,
    const float* __restrict__ qbias, const float* __restrict__ vbias,
    __bf16* __restrict__ qkvout,
    float* __restrict__ fout, const float* __restrict__ fbias)
{
    __shared__ __bf16 As[3][128 * 32];
    __shared__ __bf16 Bs[3][128 * 32];
    const int tid = threadIdx.x;
    const int chunk = (784 * NBY) >> 3;
    const int wg = (blockIdx.x & 7) * chunk + (blockIdx.x >> 3);
    const int gx = wg / NBY, gy = wg - (wg / NBY) * NBY;
    const int lane = tid & 63;
    const int wid = tid >> 6;
    const int wr = (wid >> 1) * 64;
    const int wc = (wid & 1) * 64;
    const int fr = lane & 15;
    const int fq = lane >> 4;

    f32x4 acc[4][4];
#pragma unroll
    for (int m = 0; m < 4; ++m)
#pragma unroll
        for (int n = 0; n < 4; ++n)
            acc[m][n] = (f32x4){0.f, 0.f, 0.f, 0.f};

    const int srow0 = tid >> 2, scp0 = tid & 3;
    const int srow1 = (256 + tid) >> 2;
    const size_t ar0 = (size_t)(gx * 128 + srow0) * CDIM + (scp0 ^ ((srow0 >> 1) & 3)) * 8;
    const size_t ar1 = (size_t)(gx * 128 + srow1) * CDIM + (scp0 ^ ((srow1 >> 1) & 3)) * 8;
    const size_t br0 = (size_t)(gy * 128 + srow0) * CDIM + (scp0 ^ ((srow0 >> 1) & 3)) * 8;
    const size_t br1 = (size_t)(gy * 128 + srow1) * CDIM + (scp0 ^ ((srow1 >> 1) & 3)) * 8;
    const int ls0 = tid * 16, ls1 = (256 + tid) * 16;

#define STAGE(ti, buf) do {                                              \
        const int kk_ = (ti) * 32;                                       \
        gload_lds16(A + ar0 + kk_, (char*)&As[buf][0] + ls0);            \
        gload_lds16(A + ar1 + kk_, (char*)&As[buf][0] + ls1);            \
        gload_lds16(Bw + br0 + kk_, (char*)&Bs[buf][0] + ls0);           \
        gload_lds16(Bw + br1 + kk_, (char*)&Bs[buf][0] + ls1);           \
    } while (0)

    STAGE(0, 0);
    STAGE(1, 1);

#pragma unroll
    for (int t = 0; t < 12; ++t) {
        if (t < 11) asm volatile("s_waitcnt vmcnt(4)" ::: "memory");
        else        asm volatile("s_waitcnt vmcnt(0)" ::: "memory");
        __builtin_amdgcn_s_barrier();
        if (t + 2 < 12) STAGE(t + 2, (t + 2) % 3);
        const int cur = t % 3;
        bf16x8 af[4], bfr[4];
#pragma unroll
        for (int m = 0; m < 4; ++m) {
            const int row = wr + m * 16 + fr;
            af[m] = *(const bf16x8*)&As[cur][row * 32 + (fq ^ ((row >> 1) & 3)) * 8];
        }
#pragma unroll
        for (int n = 0; n < 4; ++n) {
            const int row = wc + n * 16 + fr;
            bfr[n] = *(const bf16x8*)&Bs[cur][row * 32 + (fq ^ ((row >> 1) & 3)) * 8];
        }
#pragma unroll
        for (int m = 0; m < 4; ++m)
#pragma unroll
            for (int n = 0; n < 4; ++n)
                acc[m][n] = __builtin_amdgcn_mfma_f32_16x16x32_bf16(af[m], bfr[n], acc[m][n], 0, 0, 0);
    }
#undef STAGE

    if (MODE == 0) {
        const int colbase = gy * 128;
        const int part = colbase / CDIM;
        const int pcolbase = colbase - part * CDIM;
#pragma unroll
        for (int m = 0; m < 4; ++m) {
#pragma unroll
            for (int r = 0; r < 4; ++r) {
                const int row = gx * 128 + wr + m * 16 + fq * 4 + r;
                __bf16* orow = qkvout + (size_t)row * QKVROW + colbase + wc;
#pragma unroll
                for (int n = 0; n < 4; ++n) {
                    const int pcol = pcolbase + wc + n * 16 + fr;
                    float val = acc[m][n][r];
                    if (part == 0) val += qbias[pcol];
                    if (part == 2) val += vbias[pcol];
                    orow[n * 16 + fr] = (__bf16)val;
                }
            }
        }
    } else {
#pragma unroll
        for (int m = 0; m < 4; ++m) {
#pragma unroll
            for (int r = 0; r < 4; ++r) {
                const int row = gx * 128 + wr + m * 16 + fq * 4 + r;
                float* orow = fout + (size_t)row * CDIM + gy * 128 + wc;
#pragma unroll
                for (int n = 0; n < 4; ++n) {
                    const int col = gy * 128 + wc + n * 16 + fr;
                    orow[n * 16 + fr] = acc[m][n][r] + fbias[col];
                }
            }
        }
    }
}

// ---------------- attention (R16 verbatim: flat qkv, f32x4 bias tiles) ----------------
#define WREG 15872
__global__ __launch_bounds__(256) void attn2(
    const __bf16* __restrict__ qkv, const float* __restrict__ biasC,
    const float* __restrict__ lscale, __bf16* __restrict__ aout)
{
    __shared__ char smem[4 * WREG];
    const int tid = threadIdx.x;
    const int wid = tid >> 6, lane = tid & 63;
    const int bh = blockIdx.x * 4 + wid;
    const int b = bh / NH, h = bh - b * NH;
    const int w = b & (NWIN - 1);
    const int c = lane & 15, g = lane >> 4;

    char* base = smem + wid * WREG;
    __bf16* Kl = (__bf16*)base;
    __bf16* Ql = (__bf16*)(base + 5120);
    __bf16* Vl = (__bf16*)(base + 10240);
    float* invq = (float*)(base + 15360);
    float* invk = (float*)(base + 15616);
    char* Pl = base;

    const float sc = __expf(fminf(lscale[h], 4.6051702f));

    {
        const int row = lane;
        const size_t rb = ((size_t)b * NTOK + row) * QKVROW + h * HD;
        bf16x8 z;
#pragma unroll
        for (int e = 0; e < 8; ++e) z[e] = (__bf16)0.f;
        {
            bf16x8 t[4];
            float ss = 0.f;
            if (row < NTOK) {
#pragma unroll
                for (int ch = 0; ch < 4; ++ch) {
                    t[ch] = *(const bf16x8*)(qkv + rb + ch * 8);
#pragma unroll
                    for (int e = 0; e < 8; ++e) { float f = (float)t[ch][e]; ss += f * f; }
                }
            } else {
#pragma unroll
                for (int ch = 0; ch < 4; ++ch) t[ch] = z;
            }
#pragma unroll
            for (int ch = 0; ch < 4; ++ch) *(bf16x8*)&Ql[row * 40 + ch * 8] = t[ch];
            invq[row] = sc / fmaxf(sqrtf(ss), 1e-12f);
        }
        {
            bf16x8 t[4];
            float ss = 0.f;
            if (row < NTOK) {
#pragma unroll
                for (int ch = 0; ch < 4; ++ch) {
                    t[ch] = *(const bf16x8*)(qkv + rb + CDIM + ch * 8);
#pragma unroll
                    for (int e = 0; e < 8; ++e) { float f = (float)t[ch][e]; ss += f * f; }
                }
            } else {
#pragma unroll
                for (int ch = 0; ch < 4; ++ch) t[ch] = z;
            }
#pragma unroll
            for (int ch = 0; ch < 4; ++ch) *(bf16x8*)&Kl[row * 40 + ch * 8] = t[ch];
            invk[row] = 1.f / fmaxf(sqrtf(ss), 1e-12f);
        }
        {
            bf16x8 t[4];
            if (row < NTOK) {
#pragma unroll
                for (int ch = 0; ch < 4; ++ch) t[ch] = *(const bf16x8*)(qkv + rb + 2 * CDIM + ch * 8);
            } else {
#pragma unroll
                for (int ch = 0; ch < 4; ++ch) t[ch] = z;
            }
#pragma unroll
            for (int ch = 0; ch < 4; ++ch) *(bf16x8*)&Vl[row * 40 + ch * 8] = t[ch];
        }
    }

    bf16x8 kfr[4], qfr[4];
#pragma unroll
    for (int mt = 0; mt < 4; ++mt) kfr[mt] = *(const bf16x8*)&Kl[(mt * 16 + c) * 40 + g * 8];
#pragma unroll
    for (int nt = 0; nt < 4; ++nt) qfr[nt] = *(const bf16x8*)&Ql[(nt * 16 + c) * 40 + g * 8];
    f32x4 S[4][4];
#pragma unroll
    for (int mt = 0; mt < 4; ++mt)
#pragma unroll
        for (int nt = 0; nt < 4; ++nt) {
            S[mt][nt] = (f32x4){0.f, 0.f, 0.f, 0.f};
            S[mt][nt] = __builtin_amdgcn_mfma_f32_16x16x32_bf16(kfr[mt], qfr[nt], S[mt][nt], 0, 0, 0);
        }

    // ---- scale + combined bias (f32x4 per (mt,nt) from [q][BCROW] tile) ----
    const float* bc = biasC + (size_t)(w * NH + h) * BCTILE;
    float ivq[4];
#pragma unroll
    for (int nt = 0; nt < 4; ++nt) ivq[nt] = invq[nt * 16 + c];
#pragma unroll
    for (int mt = 0; mt < 4; ++mt) {
        const int k0 = mt * 16 + g * 4;
#pragma unroll
        for (int nt = 0; nt < 4; ++nt) {
            const int q = nt * 16 + c;
            f32x4 bv = (f32x4){0.f, 0.f, 0.f, 0.f};
            if (q < NTOK) bv = *(const f32x4*)(bc + q * BCROW + k0);
#pragma unroll
            for (int r = 0; r < 4; ++r) {
                const int k = k0 + r;
                float v = S[mt][nt][r] * invk[k] * ivq[nt];
                if (k < NTOK) {
                    if (q < NTOK) v += bv[r];
                } else {
                    v = -1e30f;
                }
                S[mt][nt][r] = v;
            }
        }
    }

    float rs[4];
#pragma unroll
    for (int nt = 0; nt < 4; ++nt) {
        float m = -1e30f;
#pragma unroll
        for (int mt = 0; mt < 4; ++mt)
#pragma unroll
            for (int r = 0; r < 4; ++r) m = fmaxf(m, S[mt][nt][r]);
        m = fmaxf(m, __shfl_xor(m, 16));
        m = fmaxf(m, __shfl_xor(m, 32));
        float s = 0.f;
#pragma unroll
        for (int mt = 0; mt < 4; ++mt)
#pragma unroll
            for (int r = 0; r < 4; ++r) {
                float e = __expf(S[mt][nt][r] - m);
                S[mt][nt][r] = e;
                s += e;
            }
        s += __shfl_xor(s, 16);
        s += __shfl_xor(s, 32);
        rs[nt] = 1.f / s;
    }

#pragma unroll
    for (int mt = 0; mt < 4; ++mt)
#pragma unroll
        for (int nt = 0; nt < 4; ++nt) {
            bf16x4 pk;
#pragma unroll
            for (int r = 0; r < 4; ++r) pk[r] = (__bf16)(S[mt][nt][r] * rs[nt]);
            *(bf16x4*)(Pl + (nt * 16 + c) * 144 + (mt * 16 + g * 4) * 2) = pk;
        }

    bf16x8 vfr[2][2];
#pragma unroll
    for (int kt = 0; kt < 2; ++kt)
#pragma unroll
        for (int dt = 0; dt < 2; ++dt) {
            bf16x8 t;
#pragma unroll
            for (int e = 0; e < 8; ++e) t[e] = Vl[(kt * 32 + g * 8 + e) * 40 + dt * 16 + c];
            vfr[kt][dt] = t;
        }
    f32x4 O[4][2];
#pragma unroll
    for (int mt = 0; mt < 4; ++mt)
#pragma unroll
        for (int dt = 0; dt < 2; ++dt) O[mt][dt] = (f32x4){0.f, 0.f, 0.f, 0.f};
#pragma unroll
    for (int mt = 0; mt < 4; ++mt)
#pragma unroll
        for (int kt = 0; kt < 2; ++kt) {
            bf16x8 pfr = *(const bf16x8*)(Pl + (mt * 16 + c) * 144 + kt * 64 + g * 16);
#pragma unroll
            for (int dt = 0; dt < 2; ++dt)
                O[mt][dt] = __builtin_amdgcn_mfma_f32_16x16x32_bf16(pfr, vfr[kt][dt], O[mt][dt], 0, 0, 0);
        }

#pragma unroll
    for (int mt = 0; mt < 4; ++mt)
#pragma unroll
        for (int r = 0; r < 4; ++r) {
            const int q = mt * 16 + g * 4 + r;
            if (q < NTOK) {
                const size_t off = ((size_t)b * NTOK + q) * CDIM + h * HD;
                aout[off + c] = (__bf16)O[mt][0][r];
                aout[off + 16 + c] = (__bf16)O[mt][1][r];
            }
        }
}

extern "C" void kernel_launch(void* const* d_in, const int* in_sizes, int n_in,
                              void* d_out, int out_size, void* d_ws, size_t ws_size,
                              hipStream_t stream) {
    const float* x      = (const float*)d_in[0];
    const float* mask   = (const float*)d_in[1];
    const float* qkv_w  = (const float*)d_in[2];
    const float* q_bias = (const float*)d_in[3];
    const float* v_bias = (const float*)d_in[4];
    const float* lscale = (const float*)d_in[5];
    const float* cpb_w1 = (const float*)d_in[6];
    const float* cpb_b1 = (const float*)d_in[7];
    const float* cpb_w2 = (const float*)d_in[8];
    const float* proj_w = (const float*)d_in[9];
    const float* proj_b = (const float*)d_in[10];
    float* out = (float*)d_out;

    const size_t NROWS = (size_t)BWIN * NTOK;           // 100352
    __bf16* qkvbuf  = (__bf16*)d_ws;                    // flat [100352][1152]
    __bf16* xbf     = qkvbuf + NROWS * QKVROW;          // x bf16; reused as attn out
    __bf16* aoutbuf = xbf;                              // alias: lifetimes disjoint
    __bf16* qkv_wb  = xbf + NROWS * CDIM;
    __bf16* proj_wb = qkv_wb + QKVROW * CDIM;
    float*  bias_tab = (float*)(proj_wb + CDIM * CDIM); // 169*12
    float*  biasC   = bias_tab + 169 * NH;              // 768 tiles x BCTILE f32 (7.9 MB)

    hipLaunchKernelGGL(prep1, dim3(XBLKS + 296), dim3(256), 0, stream,
                       x, xbf, qkv_w, qkv_wb, proj_w, proj_wb,
                       cpb_w1, cpb_b1, cpb_w2, bias_tab);
    hipLaunchKernelGGL(prep2, dim3((NWIN * NH * NTOK * BCROW + 255) / 256), dim3(256), 0, stream,
                       bias_tab, mask, biasC);
    hipLaunchKernelGGL((gemm6<0, 9>), dim3(784 * 9), dim3(256), 0, stream,
                       xbf, qkv_wb, q_bias, v_bias, qkvbuf, (float*)nullptr,
                       (const float*)nullptr);
    hipLaunchKernelGGL(attn2, dim3(BWIN * NH / 4), dim3(256), 0, stream,
                       qkvbuf, biasC, lscale, aoutbuf);
    hipLaunchKernelGGL((gemm6<1, 3>), dim3(784 * 3), dim3(256), 0, stream,
                       aoutbuf, proj_wb, (const float*)nullptr, (const float*)nullptr,
                       (__bf16*)nullptr, out, proj_b);
}

// Round 19
// 407.674 us; speedup vs baseline: 1.0385x; 1.0355x over previous
//
#include <hip/hip_runtime.h>
#include <hip/hip_bf16.h>
#include <math.h>

#define NTOK 49
#define NH 12
#define HD 32
#define CDIM 384
#define NWIN 64
#define BWIN 2048
#define QKVROW 1152
#define BCROW 52      // bias row stride (floats), 16B-aligned
#define BCTILE 2560   // bias tile stride (floats), 16B-aligned

typedef __bf16 bf16x8 __attribute__((ext_vector_type(8)));
typedef __bf16 bf16x4 __attribute__((ext_vector_type(4)));
typedef float f32x4 __attribute__((ext_vector_type(4)));

__device__ __forceinline__ void gload_lds16(const void* g, void* l) {
    __builtin_amdgcn_global_load_lds((const __attribute__((address_space(1))) void*)g,
                                     (__attribute__((address_space(3))) void*)l, 16, 0, 0);
}

__device__ __forceinline__ void cvt8(const float* src, __bf16* dst, int i) {
    f32x4 a = *(const f32x4*)(src + (size_t)i * 8);
    f32x4 b = *(const f32x4*)(src + (size_t)i * 8 + 4);
    bf16x8 o;
#pragma unroll
    for (int e = 0; e < 4; ++e) { o[e] = (__bf16)a[e]; o[e + 4] = (__bf16)b[e]; }
    *(bf16x8*)(dst + (size_t)i * 8) = o;
}

// ---------------- prep1: block-partitioned {cvt x, cvt qkv_w, cvt proj_w, cpb MLP} ----------------
#define XBLKS 18816   // 100352*384/8/256
__global__ void prep1(const float* __restrict__ x, __bf16* __restrict__ xbf,
                      const float* __restrict__ qkv_w, __bf16* __restrict__ qkv_wb,
                      const float* __restrict__ proj_w, __bf16* __restrict__ proj_wb,
                      const float* __restrict__ w1, const float* __restrict__ b1,
                      const float* __restrict__ w2, float* __restrict__ bias_tab) {
    const int blk = blockIdx.x, tid = threadIdx.x;
    if (blk < XBLKS) {
        cvt8(x, xbf, blk * 256 + tid);
    } else if (blk < XBLKS + 216) {
        cvt8(qkv_w, qkv_wb, (blk - XBLKS) * 256 + tid);
    } else if (blk < XBLKS + 288) {
        cvt8(proj_w, proj_wb, (blk - XBLKS - 216) * 256 + tid);
    } else {
        int t = (blk - XBLKS - 288) * 256 + tid;
        if (t >= 169 * NH) return;
        int r = t / NH, h = t - (t / NH) * NH;
        int i = r / 13, j = r - (r / 13) * 13;
        float a0 = (float)(i - 6) * (8.0f / 6.0f);
        float a1 = (float)(j - 6) * (8.0f / 6.0f);
        float c0 = copysignf(log2f(fabsf(a0) + 1.0f) * (1.0f / 3.0f), a0);
        float c1 = copysignf(log2f(fabsf(a1) + 1.0f) * (1.0f / 3.0f), a1);
        float sum = 0.f;
        for (int k = 0; k < 512; ++k) {
            float hid = c0 * w1[2 * k] + c1 * w1[2 * k + 1] + b1[k];
            hid = fmaxf(hid, 0.f);
            sum += hid * w2[h * 512 + k];
        }
        bias_tab[r * NH + h] = sum;
    }
}

// ---- prep2: biasC tile [w][h], layout [q][BCROW] (k fastest): 16*sigmoid(cpb)+mask ----
__global__ void prep2(const float* __restrict__ bias_tab, const float* __restrict__ mask,
                      float* __restrict__ biasC) {
    int idx = blockIdx.x * blockDim.x + threadIdx.x;
    if (idx >= NWIN * NH * NTOK * BCROW) return;
    const int per_t = NTOK * BCROW;
    int wh = idx / per_t;
    int rem = idx - wh * per_t;
    int q = rem / BCROW, k = rem - (rem / BCROW) * BCROW;
    int w = wh / NH, h = wh - (wh / NH) * NH;
    float* dst = biasC + (size_t)wh * BCTILE + q * BCROW + k;
    if (k < NTOK) {
        int chi = q / 7, cwi = q - (q / 7) * 7;
        int chj = k / 7, cwj = k - (k / 7) * 7;
        int rpi = (chi - chj + 6) * 13 + (cwi - cwj + 6);
        float r = bias_tab[rpi * NH + h];
        *dst = 16.f / (1.f + __expf(-r)) + mask[(w * NTOK + q) * NTOK + k];
    } else {
        *dst = 0.f;
    }
}

// ---------------- MFMA GEMM (R11 verbatim): 3-buffer counted-vmcnt, all-bf16 ----------------
template <int MODE, int NBY>
__global__ __launch_bounds__(256) void gemm6(
    const __bf16* __restrict__ A, const __bf16* __restrict__ Bw,
    const float* __restrict__ qbias, const float* __restrict__ vbias,
    __bf16* __restrict__ qkvout,
    float* __restrict__ fout, const float* __restrict__ fbias)
{
    __shared__ __bf16 As[3][128 * 32];
    __shared__ __bf16 Bs[3][128 * 32];
    const int tid = threadIdx.x;
    const int chunk = (784 * NBY) >> 3;
    const int wg = (blockIdx.x & 7) * chunk + (blockIdx.x >> 3);
    const int gx = wg / NBY, gy = wg - (wg / NBY) * NBY;
    const int lane = tid & 63;
    const int wid = tid >> 6;
    const int wr = (wid >> 1) * 64;
    const int wc = (wid & 1) * 64;
    const int fr = lane & 15;
    const int fq = lane >> 4;

    f32x4 acc[4][4];
#pragma unroll
    for (int m = 0; m < 4; ++m)
#pragma unroll
        for (int n = 0; n < 4; ++n)
            acc[m][n] = (f32x4){0.f, 0.f, 0.f, 0.f};

    const int srow0 = tid >> 2, scp0 = tid & 3;
    const int srow1 = (256 + tid) >> 2;
    const size_t ar0 = (size_t)(gx * 128 + srow0) * CDIM + (scp0 ^ ((srow0 >> 1) & 3)) * 8;
    const size_t ar1 = (size_t)(gx * 128 + srow1) * CDIM + (scp0 ^ ((srow1 >> 1) & 3)) * 8;
    const size_t br0 = (size_t)(gy * 128 + srow0) * CDIM + (scp0 ^ ((srow0 >> 1) & 3)) * 8;
    const size_t br1 = (size_t)(gy * 128 + srow1) * CDIM + (scp0 ^ ((srow1 >> 1) & 3)) * 8;
    const int ls0 = tid * 16, ls1 = (256 + tid) * 16;

#define STAGE(ti, buf) do {                                              \
        const int kk_ = (ti) * 32;                                       \
        gload_lds16(A + ar0 + kk_, (char*)&As[buf][0] + ls0);            \
        gload_lds16(A + ar1 + kk_, (char*)&As[buf][0] + ls1);            \
        gload_lds16(Bw + br0 + kk_, (char*)&Bs[buf][0] + ls0);           \
        gload_lds16(Bw + br1 + kk_, (char*)&Bs[buf][0] + ls1);           \
    } while (0)

    STAGE(0, 0);
    STAGE(1, 1);

#pragma unroll
    for (int t = 0; t < 12; ++t) {
        if (t < 11) asm volatile("s_waitcnt vmcnt(4)" ::: "memory");
        else        asm volatile("s_waitcnt vmcnt(0)" ::: "memory");
        __builtin_amdgcn_s_barrier();
        if (t + 2 < 12) STAGE(t + 2, (t + 2) % 3);
        const int cur = t % 3;
        bf16x8 af[4], bfr[4];
#pragma unroll
        for (int m = 0; m < 4; ++m) {
            const int row = wr + m * 16 + fr;
            af[m] = *(const bf16x8*)&As[cur][row * 32 + (fq ^ ((row >> 1) & 3)) * 8];
        }
#pragma unroll
        for (int n = 0; n < 4; ++n) {
            const int row = wc + n * 16 + fr;
            bfr[n] = *(const bf16x8*)&Bs[cur][row * 32 + (fq ^ ((row >> 1) & 3)) * 8];
        }
#pragma unroll
        for (int m = 0; m < 4; ++m)
#pragma unroll
            for (int n = 0; n < 4; ++n)
                acc[m][n] = __builtin_amdgcn_mfma_f32_16x16x32_bf16(af[m], bfr[n], acc[m][n], 0, 0, 0);
    }
#undef STAGE

    if (MODE == 0) {
        const int colbase = gy * 128;
        const int part = colbase / CDIM;
        const int pcolbase = colbase - part * CDIM;
#pragma unroll
        for (int m = 0; m < 4; ++m) {
#pragma unroll
            for (int r = 0; r < 4; ++r) {
                const int row = gx * 128 + wr + m * 16 + fq * 4 + r;
                __bf16* orow = qkvout + (size_t)row * QKVROW + colbase + wc;
#pragma unroll
                for (int n = 0; n < 4; ++n) {
                    const int pcol = pcolbase + wc + n * 16 + fr;
                    float val = acc[m][n][r];
                    if (part == 0) val += qbias[pcol];
                    if (part == 2) val += vbias[pcol];
                    orow[n * 16 + fr] = (__bf16)val;
                }
            }
        }
    } else {
#pragma unroll
        for (int m = 0; m < 4; ++m) {
#pragma unroll
            for (int r = 0; r < 4; ++r) {
                const int row = gx * 128 + wr + m * 16 + fq * 4 + r;
                float* orow = fout + (size_t)row * CDIM + gy * 128 + wc;
#pragma unroll
                for (int n = 0; n < 4; ++n) {
                    const int col = gy * 128 + wc + n * 16 + fr;
                    orow[n * 16 + fr] = acc[m][n][r] + fbias[col];
                }
            }
        }
    }
}

// ---------------- attention (R16 + bias prefetch hoisted to kernel entry) ----------------
#define WREG 15872
__global__ __launch_bounds__(256) void attn2(
    const __bf16* __restrict__ qkv, const float* __restrict__ biasC,
    const float* __restrict__ lscale, __bf16* __restrict__ aout)
{
    __shared__ char smem[4 * WREG];
    const int tid = threadIdx.x;
    const int wid = tid >> 6, lane = tid & 63;
    const int bh = blockIdx.x * 4 + wid;
    const int b = bh / NH, h = bh - b * NH;
    const int w = b & (NWIN - 1);
    const int c = lane & 15, g = lane >> 4;

    char* base = smem + wid * WREG;
    __bf16* Kl = (__bf16*)base;
    __bf16* Ql = (__bf16*)(base + 5120);
    __bf16* Vl = (__bf16*)(base + 10240);
    float* invq = (float*)(base + 15360);
    float* invk = (float*)(base + 15616);
    char* Pl = base;

    const float sc = __expf(fminf(lscale[h], 4.6051702f));

    // ---- bias prefetch (issue-early, T14): addresses known at entry; 16 f32x4 in flight
    // under staging + norms + QK^T. VGPR cost ~64; occupancy LDS-capped (2 blk/CU) so free.
    const float* bc = biasC + (size_t)(w * NH + h) * BCTILE;
    f32x4 bvv[4][4];
#pragma unroll
    for (int mt = 0; mt < 4; ++mt) {
        const int k0 = mt * 16 + g * 4;
#pragma unroll
        for (int nt = 0; nt < 4; ++nt) {
            const int q = nt * 16 + c;
            bvv[mt][nt] = (f32x4){0.f, 0.f, 0.f, 0.f};
            if (q < NTOK) bvv[mt][nt] = *(const f32x4*)(bc + q * BCROW + k0);
        }
    }

    {
        const int row = lane;
        const size_t rb = ((size_t)b * NTOK + row) * QKVROW + h * HD;
        bf16x8 z;
#pragma unroll
        for (int e = 0; e < 8; ++e) z[e] = (__bf16)0.f;
        {
            bf16x8 t[4];
            float ss = 0.f;
            if (row < NTOK) {
#pragma unroll
                for (int ch = 0; ch < 4; ++ch) {
                    t[ch] = *(const bf16x8*)(qkv + rb + ch * 8);
#pragma unroll
                    for (int e = 0; e < 8; ++e) { float f = (float)t[ch][e]; ss += f * f; }
                }
            } else {
#pragma unroll
                for (int ch = 0; ch < 4; ++ch) t[ch] = z;
            }
#pragma unroll
            for (int ch = 0; ch < 4; ++ch) *(bf16x8*)&Ql[row * 40 + ch * 8] = t[ch];
            invq[row] = sc / fmaxf(sqrtf(ss), 1e-12f);
        }
        {
            bf16x8 t[4];
            float ss = 0.f;
            if (row < NTOK) {
#pragma unroll
                for (int ch = 0; ch < 4; ++ch) {
                    t[ch] = *(const bf16x8*)(qkv + rb + CDIM + ch * 8);
#pragma unroll
                    for (int e = 0; e < 8; ++e) { float f = (float)t[ch][e]; ss += f * f; }
                }
            } else {
#pragma unroll
                for (int ch = 0; ch < 4; ++ch) t[ch] = z;
            }
#pragma unroll
            for (int ch = 0; ch < 4; ++ch) *(bf16x8*)&Kl[row * 40 + ch * 8] = t[ch];
            invk[row] = 1.f / fmaxf(sqrtf(ss), 1e-12f);
        }
        {
            bf16x8 t[4];
            if (row < NTOK) {
#pragma unroll
                for (int ch = 0; ch < 4; ++ch) t[ch] = *(const bf16x8*)(qkv + rb + 2 * CDIM + ch * 8);
            } else {
#pragma unroll
                for (int ch = 0; ch < 4; ++ch) t[ch] = z;
            }
#pragma unroll
            for (int ch = 0; ch < 4; ++ch) *(bf16x8*)&Vl[row * 40 + ch * 8] = t[ch];
        }
    }

    bf16x8 kfr[4], qfr[4];
#pragma unroll
    for (int mt = 0; mt < 4; ++mt) kfr[mt] = *(const bf16x8*)&Kl[(mt * 16 + c) * 40 + g * 8];
#pragma unroll
    for (int nt = 0; nt < 4; ++nt) qfr[nt] = *(const bf16x8*)&Ql[(nt * 16 + c) * 40 + g * 8];
    f32x4 S[4][4];
#pragma unroll
    for (int mt = 0; mt < 4; ++mt)
#pragma unroll
        for (int nt = 0; nt < 4; ++nt) {
            S[mt][nt] = (f32x4){0.f, 0.f, 0.f, 0.f};
            S[mt][nt] = __builtin_amdgcn_mfma_f32_16x16x32_bf16(kfr[mt], qfr[nt], S[mt][nt], 0, 0, 0);
        }

    // ---- scale + combined bias (prefetched bvv) ----
    float ivq[4];
#pragma unroll
    for (int nt = 0; nt < 4; ++nt) ivq[nt] = invq[nt * 16 + c];
#pragma unroll
    for (int mt = 0; mt < 4; ++mt) {
        const int k0 = mt * 16 + g * 4;
#pragma unroll
        for (int nt = 0; nt < 4; ++nt) {
            const int q = nt * 16 + c;
#pragma unroll
            for (int r = 0; r < 4; ++r) {
                const int k = k0 + r;
                float v = S[mt][nt][r] * invk[k] * ivq[nt];
                if (k < NTOK) {
                    if (q < NTOK) v += bvv[mt][nt][r];
                } else {
                    v = -1e30f;
                }
                S[mt][nt][r] = v;
            }
        }
    }

    float rs[4];
#pragma unroll
    for (int nt = 0; nt < 4; ++nt) {
        float m = -1e30f;
#pragma unroll
        for (int mt = 0; mt < 4; ++mt)
#pragma unroll
            for (int r = 0; r < 4; ++r) m = fmaxf(m, S[mt][nt][r]);
        m = fmaxf(m, __shfl_xor(m, 16));
        m = fmaxf(m, __shfl_xor(m, 32));
        float s = 0.f;
#pragma unroll
        for (int mt = 0; mt < 4; ++mt)
#pragma unroll
            for (int r = 0; r < 4; ++r) {
                float e = __expf(S[mt][nt][r] - m);
                S[mt][nt][r] = e;
                s += e;
            }
        s += __shfl_xor(s, 16);
        s += __shfl_xor(s, 32);
        rs[nt] = 1.f / s;
    }

#pragma unroll
    for (int mt = 0; mt < 4; ++mt)
#pragma unroll
        for (int nt = 0; nt < 4; ++nt) {
            bf16x4 pk;
#pragma unroll
            for (int r = 0; r < 4; ++r) pk[r] = (__bf16)(S[mt][nt][r] * rs[nt]);
            *(bf16x4*)(Pl + (nt * 16 + c) * 144 + (mt * 16 + g * 4) * 2) = pk;
        }

    bf16x8 vfr[2][2];
#pragma unroll
    for (int kt = 0; kt < 2; ++kt)
#pragma unroll
        for (int dt = 0; dt < 2; ++dt) {
            bf16x8 t;
#pragma unroll
            for (int e = 0; e < 8; ++e) t[e] = Vl[(kt * 32 + g * 8 + e) * 40 + dt * 16 + c];
            vfr[kt][dt] = t;
        }
    f32x4 O[4][2];
#pragma unroll
    for (int mt = 0; mt < 4; ++mt)
#pragma unroll
        for (int dt = 0; dt < 2; ++dt) O[mt][dt] = (f32x4){0.f, 0.f, 0.f, 0.f};
#pragma unroll
    for (int mt = 0; mt < 4; ++mt)
#pragma unroll
        for (int kt = 0; kt < 2; ++kt) {
            bf16x8 pfr = *(const bf16x8*)(Pl + (mt * 16 + c) * 144 + kt * 64 + g * 16);
#pragma unroll
            for (int dt = 0; dt < 2; ++dt)
                O[mt][dt] = __builtin_amdgcn_mfma_f32_16x16x32_bf16(pfr, vfr[kt][dt], O[mt][dt], 0, 0, 0);
        }

#pragma unroll
    for (int mt = 0; mt < 4; ++mt)
#pragma unroll
        for (int r = 0; r < 4; ++r) {
            const int q = mt * 16 + g * 4 + r;
            if (q < NTOK) {
                const size_t off = ((size_t)b * NTOK + q) * CDIM + h * HD;
                aout[off + c] = (__bf16)O[mt][0][r];
                aout[off + 16 + c] = (__bf16)O[mt][1][r];
            }
        }
}

extern "C" void kernel_launch(void* const* d_in, const int* in_sizes, int n_in,
                              void* d_out, int out_size, void* d_ws, size_t ws_size,
                              hipStream_t stream) {
    const float* x      = (const float*)d_in[0];
    const float* mask   = (const float*)d_in[1];
    const float* qkv_w  = (const float*)d_in[2];
    const float* q_bias = (const float*)d_in[3];
    const float* v_bias = (const float*)d_in[4];
    const float* lscale = (const float*)d_in[5];
    const float* cpb_w1 = (const float*)d_in[6];
    const float* cpb_b1 = (const float*)d_in[7];
    const float* cpb_w2 = (const float*)d_in[8];
    const float* proj_w = (const float*)d_in[9];
    const float* proj_b = (const float*)d_in[10];
    float* out = (float*)d_out;

    const size_t NROWS = (size_t)BWIN * NTOK;           // 100352
    __bf16* qkvbuf  = (__bf16*)d_ws;                    // flat [100352][1152]
    __bf16* xbf     = qkvbuf + NROWS * QKVROW;          // x bf16; reused as attn out
    __bf16* aoutbuf = xbf;                              // alias: lifetimes disjoint
    __bf16* qkv_wb  = xbf + NROWS * CDIM;
    __bf16* proj_wb = qkv_wb + QKVROW * CDIM;
    float*  bias_tab = (float*)(proj_wb + CDIM * CDIM); // 169*12
    float*  biasC   = bias_tab + 169 * NH;              // 768 tiles x BCTILE f32 (7.9 MB)

    hipLaunchKernelGGL(prep1, dim3(XBLKS + 296), dim3(256), 0, stream,
                       x, xbf, qkv_w, qkv_wb, proj_w, proj_wb,
                       cpb_w1, cpb_b1, cpb_w2, bias_tab);
    hipLaunchKernelGGL(prep2, dim3((NWIN * NH * NTOK * BCROW + 255) / 256), dim3(256), 0, stream,
                       bias_tab, mask, biasC);
    hipLaunchKernelGGL((gemm6<0, 9>), dim3(784 * 9), dim3(256), 0, stream,
                       xbf, qkv_wb, q_bias, v_bias, qkvbuf, (float*)nullptr,
                       (const float*)nullptr);
    hipLaunchKernelGGL(attn2, dim3(BWIN * NH / 4), dim3(256), 0, stream,
                       qkvbuf, biasC, lscale, aoutbuf);
    hipLaunchKernelGGL((gemm6<1, 3>), dim3(784 * 3), dim3(256), 0, stream,
                       aoutbuf, proj_wb, (const float*)nullptr, (const float*)nullptr,
                       (__bf16*)nullptr, out, proj_b);
}